// Round 4
// baseline (177.101 us; speedup 1.0000x reference)
//
#include <hip/hip_runtime.h>
#include <hip/hip_bf16.h>
#include <cstdint>

typedef __bf16 bf16x8 __attribute__((ext_vector_type(8)));
typedef float f32x4 __attribute__((ext_vector_type(4)));

__device__ inline unsigned short f2bf(float f) {
  union { float f; unsigned u; } x; x.f = f;
  unsigned r = x.u + 0x7fffu + ((x.u >> 16) & 1u);
  return (unsigned short)(r >> 16);
}
__device__ inline float bf2f(unsigned short b) {
  union { unsigned u; float f; } x; x.u = ((unsigned)b) << 16;
  return x.f;
}

__device__ inline void gload_lds16(const void* g, void* l) {
  __builtin_amdgcn_global_load_lds(
      (const __attribute__((address_space(1))) unsigned int*)g,
      (__attribute__((address_space(3))) unsigned int*)l, 16, 0, 0);
}

// C = A * B^T (+bias). A[M,K], B[N,K] row-major bf16. BK=64.
// 8 waves (2M x 4N). Wave tile (MI*16) x (NI*16). BM=2*MI*16, BN=4*NI*16.
// LDS per slot, kk-major: A0[BM][32] A1[BM][32] B0[BN][32] B1[BN][32] (64B row
// stride => bank-conflict-free ds_read_b128 AND contiguous half-tile DMA).
// 2 slots double-buffer; m201 lifecycle: ph1{rd A0,B0; stage A1B1(t+1)},
// ph2{rd A1,B1; stage A0B0(t+2); vmcnt(2*LPH)}; double barrier per phase.
// MODE 0: fused QKV: by>>2 = weight w (0:K->C0, 1:Q->C1, 2:V->C2 transposed).
// MODE 2: scores: bf16 = acc*scale, skip blocks above causal diagonal.
// MODE 3: PV: f32 = acc, K bounded; 1D LPT grid (longest blocks first).
template <int MODE, int MI, int NI, int MINW>
__global__ __launch_bounds__(512, MINW) void gemm3(
    const unsigned short* __restrict__ A, int lda, long long sA,
    const unsigned short* __restrict__ B0, int ldb, long long sB,
    void* __restrict__ C0, int ldc, long long sC,
    const float* __restrict__ b0, const float* __restrict__ b1, const float* __restrict__ b2,
    void* __restrict__ C1, void* __restrict__ C2,
    int K, float scale)
{
  constexpr int BM = 2 * MI * 16;
  constexpr int BN = 4 * NI * 16;
  constexpr int AR = BM * 32;           // elems per A kk-half
  constexpr int BR = BN * 32;
  constexpr int SLOT = (BM + BN) * 64;
  constexpr int LPH = BM / 128;         // gloads per half per thread (BM==BN here)

  extern __shared__ unsigned short lds[];

  int bx, by, bz = 0, w = 0;
  if (MODE == 3) {
    const int i = blockIdx.x;           // LPT: longest K first
    bx = 15 - (i >> 5);
    by = i & 7; bz = (i >> 3) & 3;
  } else {
    bx = blockIdx.x; by = blockIdx.y; bz = blockIdx.z;
  }
  const int brow0 = bx * BM;
  int bcol0;
  const unsigned short* Bp;
  if (MODE == 0) {
    w = by >> 2; bcol0 = (by & 3) * BN;
    Bp = B0 + ((size_t)w << 20);
  } else {
    bcol0 = by * BN;
    Bp = B0 + (size_t)bz * sB;
    if (MODE == 2 && bcol0 > brow0 + BM - 1) return;
  }
  const unsigned short* Ap = A + (size_t)bz * sA;
  const int kend = (MODE == 3) ? min(K, brow0 + BM) : K;
  const int nt = kend >> 6;

  const int tid = threadIdx.x;
  const int wid = tid >> 6, lane = tid & 63;
  const int wr = wid >> 2, wc = wid & 3;
  const int frow = lane & 15, fk = (lane >> 4) * 8;

  // fragment LDS elem offsets (within slot), conflict-free by construction
  int aoff[2][MI], boff[2][NI];
  #pragma unroll
  for (int kk = 0; kk < 2; ++kk) {
    #pragma unroll
    for (int mi = 0; mi < MI; ++mi)
      aoff[kk][mi] = kk * AR + (wr * MI * 16 + mi * 16 + frow) * 32 + fk;
    #pragma unroll
    for (int ni = 0; ni < NI; ++ni)
      boff[kk][ni] = BM * 64 + kk * BR + (wc * NI * 16 + ni * 16 + frow) * 32 + fk;
  }

  f32x4 acc[MI][NI];
  #pragma unroll
  for (int i = 0; i < MI; ++i)
    #pragma unroll
    for (int j = 0; j < NI; ++j) acc[i][j] = (f32x4){0.f, 0.f, 0.f, 0.f};

  // stage one half-tile (matrix m: 0=A, 1=B; kk half) of tile with k0, into slot
  auto stage = [&](unsigned short* sp, int k0, int m, int kk) {
    #pragma unroll
    for (int i = 0; i < LPH; ++i) {
      const int e = (i * 512 + tid) * 8;  // elem within half
      const int r = e >> 5, c = e & 31;
      if (m == 0)
        gload_lds16(Ap + (size_t)(brow0 + r) * lda + k0 + kk * 32 + c, &sp[kk * AR + e]);
      else
        gload_lds16(Bp + (size_t)(bcol0 + r) * ldb + k0 + kk * 32 + c, &sp[BM * 64 + kk * BR + e]);
    }
  };

  // prologue: t0 all 4 halves; t1 {A0,B0}; wait t0 (leave t1's in flight)
  stage(&lds[0], 0, 0, 0); stage(&lds[0], 0, 1, 0);
  stage(&lds[0], 0, 0, 1); stage(&lds[0], 0, 1, 1);
  if (1 < nt) { stage(&lds[SLOT], 64, 0, 0); stage(&lds[SLOT], 64, 1, 0); }
  if constexpr (LPH == 2) asm volatile("s_waitcnt vmcnt(4)" ::: "memory");
  else                    asm volatile("s_waitcnt vmcnt(2)" ::: "memory");
  __builtin_amdgcn_s_barrier();

  #pragma unroll 1
  for (int t = 0; t < nt; ++t) {
    unsigned short* sb = &lds[(t & 1) * SLOT];
    unsigned short* sn = &lds[((t + 1) & 1) * SLOT];
    const int k1 = (t + 1) << 6, k2 = (t + 2) << 6;

    // ---- phase 1: kk=0 ----
    {
      bf16x8 af[MI], bf[NI];
      #pragma unroll
      for (int i = 0; i < MI; ++i) af[i] = *(const bf16x8*)&sb[aoff[0][i]];
      #pragma unroll
      for (int i = 0; i < NI; ++i) bf[i] = *(const bf16x8*)&sb[boff[0][i]];
      if (t + 1 < nt) { stage(sn, k1, 0, 1); stage(sn, k1, 1, 1); }  // A1,B1 of t+1
      __builtin_amdgcn_s_barrier();
      __builtin_amdgcn_s_setprio(1);
      #pragma unroll
      for (int mi = 0; mi < MI; ++mi)
        #pragma unroll
        for (int ni = 0; ni < NI; ++ni)
          acc[mi][ni] = __builtin_amdgcn_mfma_f32_16x16x32_bf16(af[mi], bf[ni], acc[mi][ni], 0, 0, 0);
      __builtin_amdgcn_s_setprio(0);
      __builtin_amdgcn_s_barrier();
    }
    // ---- phase 2: kk=1 ----
    {
      bf16x8 af[MI], bf[NI];
      #pragma unroll
      for (int i = 0; i < MI; ++i) af[i] = *(const bf16x8*)&sb[aoff[1][i]];
      #pragma unroll
      for (int i = 0; i < NI; ++i) bf[i] = *(const bf16x8*)&sb[boff[1][i]];
      if (t + 2 < nt) { stage(sb, k2, 0, 0); stage(sb, k2, 1, 0); }  // A0,B0 of t+2
      if (t + 2 < nt) {
        if constexpr (LPH == 2) asm volatile("s_waitcnt vmcnt(4)" ::: "memory");
        else                    asm volatile("s_waitcnt vmcnt(2)" ::: "memory");
      } else if (t + 1 < nt) {
        asm volatile("s_waitcnt vmcnt(0)" ::: "memory");
      }
      __builtin_amdgcn_s_barrier();
      __builtin_amdgcn_s_setprio(1);
      #pragma unroll
      for (int mi = 0; mi < MI; ++mi)
        #pragma unroll
        for (int ni = 0; ni < NI; ++ni)
          acc[mi][ni] = __builtin_amdgcn_mfma_f32_16x16x32_bf16(af[mi], bf[ni], acc[mi][ni], 0, 0, 0);
      __builtin_amdgcn_s_setprio(0);
      __builtin_amdgcn_s_barrier();
    }
  }

  // epilogue: C/D layout col=lane&15, row=(lane>>4)*4+reg
  const float* bias = nullptr;
  if (MODE == 0) bias = (w == 0) ? b0 : (w == 1) ? b1 : b2;

  #pragma unroll
  for (int mi = 0; mi < MI; ++mi) {
    #pragma unroll
    for (int ni = 0; ni < NI; ++ni) {
      const int row0 = brow0 + wr * MI * 16 + mi * 16 + (lane >> 4) * 4;
      const int col = bcol0 + wc * NI * 16 + ni * 16 + frow;
      if (MODE == 0) {
        const float bv = bias[col];
        if (w == 2) {
          unsigned short* Cb = (unsigned short*)C2;
          const int bb = row0 >> 11, s0 = row0 & 2047;
          ushort4 pk;
          pk.x = f2bf(acc[mi][ni][0] + bv);
          pk.y = f2bf(acc[mi][ni][1] + bv);
          pk.z = f2bf(acc[mi][ni][2] + bv);
          pk.w = f2bf(acc[mi][ni][3] + bv);
          *(ushort4*)&Cb[(size_t)bb * (1024 * 2048) + (size_t)col * 2048 + s0] = pk;
        } else {
          unsigned short* Cb = (unsigned short*)(w == 0 ? C0 : C1);
          #pragma unroll
          for (int r = 0; r < 4; ++r)
            Cb[(size_t)(row0 + r) * ldc + col] = f2bf(acc[mi][ni][r] + bv);
        }
      } else if (MODE == 2) {
        unsigned short* Cb = (unsigned short*)C0 + (size_t)bz * sC;
        #pragma unroll
        for (int r = 0; r < 4; ++r)
          Cb[(size_t)(row0 + r) * ldc + col] = f2bf(acc[mi][ni][r] * scale);
      } else {
        float* Cf = (float*)C0 + (size_t)bz * sC;
        #pragma unroll
        for (int r = 0; r < 4; ++r)
          Cf[(size_t)(row0 + r) * ldc + col] = acc[mi][ni][r];
      }
    }
  }
}

// in-place causal softmax, trimmed to the 128-col-rounded causal prefix
// (PV reads exactly j < ((i>>7)+1)*128, so untouched tails are never consumed)
__global__ __launch_bounds__(256) void softmax_causal(unsigned short* __restrict__ Sc) {
  const int row = blockIdx.x;     // b*2048 + i
  const int i = row & 2047;
  const int nc = ((i >> 7) + 1) * 128;
  unsigned short* rp = Sc + (size_t)row * 2048;
  const int t = threadIdx.x;
  const int j0 = t * 8;
  const bool act = (j0 < nc);

  float v[8];
  if (act) {
    uint4 raw = ((const uint4*)rp)[t];
    unsigned us[8];
    us[0] = raw.x & 0xffffu; us[1] = raw.x >> 16;
    us[2] = raw.y & 0xffffu; us[3] = raw.y >> 16;
    us[4] = raw.z & 0xffffu; us[5] = raw.z >> 16;
    us[6] = raw.w & 0xffffu; us[7] = raw.w >> 16;
    #pragma unroll
    for (int e = 0; e < 8; ++e) v[e] = bf2f((unsigned short)us[e]);
  } else {
    #pragma unroll
    for (int e = 0; e < 8; ++e) v[e] = 0.f;
  }

  float m = -3.0e38f;
  if (act) {
    #pragma unroll
    for (int e = 0; e < 8; ++e) if (j0 + e <= i) m = fmaxf(m, v[e]);
  }
  #pragma unroll
  for (int o = 32; o > 0; o >>= 1) m = fmaxf(m, __shfl_xor(m, o));

  __shared__ float red[8];
  const int wid = t >> 6, lane = t & 63;
  if (lane == 0) red[wid] = m;
  __syncthreads();
  m = fmaxf(fmaxf(red[0], red[1]), fmaxf(red[2], red[3]));

  float ev[8];
  float s = 0.f;
  #pragma unroll
  for (int e = 0; e < 8; ++e) {
    float x = (act && j0 + e <= i) ? __expf(v[e] - m) : 0.f;
    ev[e] = x; s += x;
  }
  #pragma unroll
  for (int o = 32; o > 0; o >>= 1) s += __shfl_xor(s, o);
  if (lane == 0) red[4 + wid] = s;
  __syncthreads();
  s = red[4] + red[5] + red[6] + red[7];
  const float inv = 1.f / s;

  if (act) {
    uint4 outw;
    outw.x = (unsigned)f2bf(ev[0] * inv) | ((unsigned)f2bf(ev[1] * inv) << 16);
    outw.y = (unsigned)f2bf(ev[2] * inv) | ((unsigned)f2bf(ev[3] * inv) << 16);
    outw.z = (unsigned)f2bf(ev[4] * inv) | ((unsigned)f2bf(ev[5] * inv) << 16);
    outw.w = (unsigned)f2bf(ev[6] * inv) | ((unsigned)f2bf(ev[7] * inv) << 16);
    ((uint4*)rp)[t] = outw;
  }
}

__global__ __launch_bounds__(256) void cvt_f32_bf16(const float4* __restrict__ in,
                                                    ushort4* __restrict__ out, int n4) {
  const int idx = blockIdx.x * 256 + threadIdx.x;
  if (idx >= n4) return;
  float4 f = in[idx];
  ushort4 o;
  o.x = f2bf(f.x); o.y = f2bf(f.y); o.z = f2bf(f.z); o.w = f2bf(f.w);
  out[idx] = o;
}

__global__ __launch_bounds__(256) void cvt_w3(const float4* __restrict__ w0,
                                              const float4* __restrict__ w1,
                                              const float4* __restrict__ w2,
                                              ushort4* __restrict__ out) {
  const int g = blockIdx.x;            // [0,3072)
  const int sel = g >> 10;
  const int idx = (g & 1023) * 256 + threadIdx.x;
  const float4* in = (sel == 0) ? w0 : (sel == 1) ? w1 : w2;
  float4 f = in[idx];
  ushort4 o;
  o.x = f2bf(f.x); o.y = f2bf(f.y); o.z = f2bf(f.z); o.w = f2bf(f.w);
  out[(size_t)sel * 262144 + idx] = o;
}

#define LDS_BIG 131072   // 2 slots * (256+256)*64 * 2B
#define LDS_PV   65536   // 2 slots * (128+128)*64 * 2B

extern "C" void kernel_launch(void* const* d_in, const int* in_sizes, int n_in,
                              void* d_out, int out_size, void* d_ws, size_t ws_size,
                              hipStream_t stream) {
  const float* x  = (const float*)d_in[0];
  const float* Wk = (const float*)d_in[1];
  const float* bk = (const float*)d_in[2];
  const float* Wq = (const float*)d_in[3];
  const float* bq = (const float*)d_in[4];
  const float* Wv = (const float*)d_in[5];
  const float* bv = (const float*)d_in[6];
  float* out = (float*)d_out;

  char* ws = (char*)d_ws;
  unsigned short* xb = (unsigned short*)(ws + 0);          // 8192x1024 bf16  (16 MB)
  unsigned short* Wb = (unsigned short*)(ws + 16777216);   // 3 x 1024x1024   (6 MB)
  unsigned short* Kb = (unsigned short*)(ws + 23068672);   // 8192x1024       (16 MB)
  unsigned short* Qb = (unsigned short*)(ws + 39845888);   // 8192x1024       (16 MB)
  unsigned short* Vt = (unsigned short*)(ws + 56623104);   // 4 x 1024x2048   (16 MB)
  unsigned short* Sc = (unsigned short*)(ws + 73400320);   // 4 x 2048x2048   (32 MB)

  (void)hipFuncSetAttribute(reinterpret_cast<const void*>(&gemm3<0, 8, 4, 2>),
                            hipFuncAttributeMaxDynamicSharedMemorySize, LDS_BIG);
  (void)hipFuncSetAttribute(reinterpret_cast<const void*>(&gemm3<2, 8, 4, 2>),
                            hipFuncAttributeMaxDynamicSharedMemorySize, LDS_BIG);
  (void)hipFuncSetAttribute(reinterpret_cast<const void*>(&gemm3<3, 4, 2, 4>),
                            hipFuncAttributeMaxDynamicSharedMemorySize, LDS_PV);

  cvt_f32_bf16<<<8192, 256, 0, stream>>>((const float4*)x, (ushort4*)xb, 2097152);
  cvt_w3<<<3072, 256, 0, stream>>>((const float4*)Wk, (const float4*)Wq, (const float4*)Wv,
                                   (ushort4*)Wb);

  // fused QKV, 256x256 tiles: grid (32, 3 weights x 4 col-blocks) = 384 blocks
  gemm3<0, 8, 4, 2><<<dim3(32, 12, 1), 512, LDS_BIG, stream>>>(
      xb, 1024, 0, Wb, 1024, 0, Kb, 1024, 0, bk, bq, bv, Qb, Vt, 1024, 1.f);

  // scores = Q K^T / 32, 256x256 tiles, causal lower-tri blocks only
  gemm3<2, 8, 4, 2><<<dim3(8, 8, 4), 512, LDS_BIG, stream>>>(
      Qb, 1024, 2048LL * 1024, Kb, 1024, 2048LL * 1024,
      Sc, 2048, 2048LL * 2048, nullptr, nullptr, nullptr, nullptr, nullptr, 1024, 0.03125f);

  softmax_causal<<<8192, 256, 0, stream>>>(Sc);

  // out = P @ V, 128x128 tiles, causal K-bound, LPT 1D grid (512 blocks, 2/CU)
  gemm3<3, 4, 2, 4><<<dim3(512, 1, 1), 512, LDS_PV, stream>>>(
      Sc, 2048, 2048LL * 2048, Vt, 2048, 1024LL * 2048,
      out, 1024, 2048LL * 1024, nullptr, nullptr, nullptr, nullptr, nullptr, 2048, 1.f);
}